// Round 16
// baseline (289.324 us; speedup 1.0000x reference)
//
#include <hip/hip_runtime.h>
#include <math.h>

#define TT 8192
#define HH 5120
#define EE 160
#define NGRP 8
#define GSZ 20
#define TOPKG 3
#define TOPK 6
#define RSCALE 16.0f
#define SK 8              // split-K factor
#define KS (HH / SK)      // 640 K per slice
#define NSG (KS / 32)     // 20 K32 steps per gemm block
#define BMG 128           // tokens per gemm block -> grid 64*8=512, 2 blocks/CU
#define NMB (TT / BMG)    // 64 token-blocks

typedef __attribute__((ext_vector_type(8))) short bf16x8;
typedef __attribute__((ext_vector_type(8))) _Float16 f16x8;
typedef __attribute__((ext_vector_type(4))) float f32x4;

#define BW_ELEMS ((size_t)160 * 10 * 64 * 8)     // 819200 frag elements per copy
#define BWH_BYTES (BW_ELEMS * 2)                 // 1,638,400 bytes (f16 single copy)

__device__ __forceinline__ ushort f2bf(float f) {
    uint32_t u = __float_as_uint(f);
    u += 0x7fff + ((u >> 16) & 1);   // RNE
    return (ushort)(u >> 16);
}
__device__ __forceinline__ float bf2f(ushort h) {
    return __uint_as_float(((uint32_t)h) << 16);
}

// pack 8 fp32 -> 8 f16 (RNE via _Float16 cast)
__device__ __forceinline__ f16x8 cvt8(f32x4 x, f32x4 y) {
    f16x8 r;
    r[0] = (_Float16)x[0]; r[1] = (_Float16)x[1];
    r[2] = (_Float16)x[2]; r[3] = (_Float16)x[3];
    r[4] = (_Float16)y[0]; r[5] = (_Float16)y[1];
    r[6] = (_Float16)y[2]; r[7] = (_Float16)y[3];
    return r;
}

// per-wave routing for one token t: reduce SK slices of P, softmax, group-topk.
// (validated math from R0/R2; all 64 lanes participate)
__device__ __forceinline__ void route_token(const float* __restrict__ P,
                                            float* __restrict__ out,
                                            int t, int l) {
    float s0 = 0.f, s1 = 0.f, s2 = 0.f;
    #pragma unroll
    for (int sl = 0; sl < SK; ++sl) {
        const float* b = P + ((size_t)sl * TT + t) * EE;
        s0 += b[l];
        s1 += b[64 + l];
        if (l < 32) s2 += b[128 + l];
    }
    if (l >= 32) s2 = -INFINITY;

    float m = fmaxf(s0, fmaxf(s1, s2));
    #pragma unroll
    for (int off = 32; off >= 1; off >>= 1) m = fmaxf(m, __shfl_xor(m, off, 64));
    float p0 = expf(s0 - m);
    float p1 = expf(s1 - m);
    float p2 = (l < 32) ? expf(s2 - m) : 0.f;
    float sum = p0 + p1 + p2;
    #pragma unroll
    for (int off = 32; off >= 1; off >>= 1) sum += __shfl_xor(sum, off, 64);
    float inv = 1.0f / sum;
    p0 *= inv; p1 *= inv; p2 *= inv;

    const int g0 = l / GSZ;
    const int g1 = (l + 64) / GSZ;
    const int g2 = (l + 128) / GSZ;

    float gmax[NGRP];
    #pragma unroll
    for (int g = 0; g < NGRP; g++) {
        float v = -1.f;
        if (g0 == g) v = p0;
        if (g1 == g) v = fmaxf(v, p1);
        if (l < 32 && g2 == g) v = fmaxf(v, p2);
        #pragma unroll
        for (int off = 32; off >= 1; off >>= 1) v = fmaxf(v, __shfl_xor(v, off, 64));
        gmax[g] = v;
    }

    int selmask = 0;
    #pragma unroll
    for (int s = 0; s < TOPKG; s++) {
        float best = -2.f; int bg = 0;
        #pragma unroll
        for (int g = 0; g < NGRP; g++)
            if (!((selmask >> g) & 1) && gmax[g] > best) { best = gmax[g]; bg = g; }
        selmask |= 1 << bg;
    }

    float m0 = ((selmask >> g0) & 1) ? p0 : 0.f;
    float m1 = ((selmask >> g1) & 1) ? p1 : 0.f;
    float m2 = (l < 32) ? (((selmask >> g2) & 1) ? p2 : 0.f) : -1.f;

    #pragma unroll
    for (int s = 0; s < TOPK; s++) {
        float v = fmaxf(m0, fmaxf(m1, m2));
        #pragma unroll
        for (int off = 32; off >= 1; off >>= 1) v = fmaxf(v, __shfl_xor(v, off, 64));
        int idx = 0x7fffffff;
        if (m0 == v) idx = l;
        if (m1 == v) idx = min(idx, l + 64);
        if (l < 32 && m2 == v) idx = min(idx, l + 128);
        #pragma unroll
        for (int off = 32; off >= 1; off >>= 1) idx = min(idx, __shfl_xor(idx, off, 64));
        if (idx == l)            m0 = -1.f;
        else if (idx == l + 64)  m1 = -1.f;
        else if (l < 32 && idx == l + 128) m2 = -1.f;
        if (l == 0) out[(size_t)t * TOPK + s] = v * RSCALE;
    }
}

// ---------------- Kernel 1: B [160][5120] fp32 -> f16 fragment-linear ----------
// Also zeroes the per-mb completion counters (re-zeroed every call -> graph-safe).
__global__ __launch_bounds__(256) void prep_b_f16(const float* __restrict__ B,
                                                  ushort* __restrict__ Bw,
                                                  int* __restrict__ done) {
    if (blockIdx.x == 0 && threadIdx.x < NMB) done[threadIdx.x] = 0;
    int gid = blockIdx.x * 256 + threadIdx.x;        // < 102400
    int lane = gid & 63;
    int et   = (gid >> 6) % 10;
    int kt   = gid / 640;
    int e = et * 16 + (lane & 15);
    int c = kt * 32 + (lane >> 4) * 8;
    const float* src = B + (size_t)e * HH + c;
    f32x4 s0 = *(const f32x4*)src;
    f32x4 s1 = *(const f32x4*)(src + 4);
    union { f16x8 h; uint4 v; } u;
    u.h = cvt8(s0, s1);
    *reinterpret_cast<uint4*>(Bw + (size_t)gid * 8) = u.v;
}

// ---------------- Kernel 2: split-K GEMM + fused completion-counter routing ----
// R14 gemm body (59.9us) + fused epilogue: after partials, release-fence +
// atomicAdd(done[mb]); the 8th arriver routes its 128 tokens (acquire fence,
// read P, validated routing). 62/64 reducers overlap remaining gemm blocks;
// removes the separate route dispatch. Deadlock-free (no spin).
__global__ __launch_bounds__(512, 4) void moe_gemm(const float* __restrict__ A,
                                                   const ushort* __restrict__ Bw,
                                                   float* __restrict__ P,
                                                   int* __restrict__ done,
                                                   float* __restrict__ out) {
    __shared__ char lds[2][10240];     // double-buffered K32 B tile (f16)

    const int tid = threadIdx.x;
    const int w = tid >> 6, l = tid & 63;
    const int mb  = blockIdx.x & 63;   // token-block (64)
    const int ks  = blockIdx.x >> 6;   // k-slice (8)
    const int bm0 = mb * BMG;
    const int kt0 = ks * NSG;          // global K32-tile base

    const int row = l & 15, koct = l >> 4;

    const float* apA = A + (size_t)(bm0 + 16 * w + row) * HH + ks * KS + koct * 8;

    const char* BwB = (const char*)Bw;
    const int u0 = tid, u1 = tid + 512;

    f32x4 acc[10];
    #pragma unroll
    for (int et = 0; et < 10; et++) acc[et] = (f32x4){0.f, 0.f, 0.f, 0.f};

    // ---- prologue: stage step 0 + load A(step 0)
    {
        size_t tb = (size_t)kt0 * 10240;
        uint4 r0 = *(const uint4*)(BwB + tb + (size_t)u0 * 16);
        *(uint4*)(lds[0] + u0 * 16) = r0;
        if (tid < 128) {
            uint4 r1 = *(const uint4*)(BwB + tb + (size_t)u1 * 16);
            *(uint4*)(lds[0] + u1 * 16) = r1;
        }
    }
    f32x4 pa0 = *(const f32x4*)(apA), pa1 = *(const f32x4*)(apA + 4);
    __syncthreads();

    #pragma unroll 1
    for (int s = 0; s < NSG; ++s) {
        const int cur = s & 1;
        const bool more = (s + 1 < NSG);

        uint4 n0, n1;
        f32x4 na0 = pa0, na1 = pa1;
        if (more) {
            size_t tb = (size_t)(kt0 + s + 1) * 10240;
            n0 = *(const uint4*)(BwB + tb + (size_t)u0 * 16);
            if (tid < 128) n1 = *(const uint4*)(BwB + tb + (size_t)u1 * 16);
            const float* a = apA + (s + 1) * 32;
            na0 = *(const f32x4*)(a); na1 = *(const f32x4*)(a + 4);
        }

        f16x8 a16 = cvt8(pa0, pa1);
        const char* LB = lds[cur];
        #pragma unroll
        for (int et = 0; et < 10; ++et) {
            f16x8 bh = *(const f16x8*)(LB + et * 1024 + l * 16);
            acc[et] = __builtin_amdgcn_mfma_f32_16x16x32_f16(a16, bh, acc[et], 0, 0, 0);
        }

        if (more) {
            char* LN = lds[1 - cur];
            *(uint4*)(LN + u0 * 16) = n0;
            if (tid < 128) *(uint4*)(LN + u1 * 16) = n1;
        }
        pa0 = na0; pa1 = na1;

        asm volatile("s_waitcnt lgkmcnt(0)" ::: "memory");
        __builtin_amdgcn_sched_barrier(0);
        __builtin_amdgcn_s_barrier();
        __builtin_amdgcn_sched_barrier(0);
    }

    // ---- write fp32 partials: P[ks][bm0 + 16w + (l>>4)*4 + j][et*16 + (l&15)]
    const int rrow = koct * 4;
    #pragma unroll
    for (int et = 0; et < 10; et++)
        #pragma unroll
        for (int j = 0; j < 4; j++)
            P[((size_t)ks * TT + bm0 + 16 * w + rrow + j) * EE + et * 16 + row]
                = acc[et][j];

    // ---- completion: release fence, count arrivals; 8th arriver routes mb
    __threadfence();                   // flush partials device-wide (cross-XCD)
    __syncthreads();                   // all threads' stores+fences done
    int* sFlag = (int*)lds;            // reuse LDS for the arrival index
    if (tid == 0) sFlag[0] = atomicAdd(&done[mb], 1);
    __syncthreads();
    if (sFlag[0] == SK - 1) {
        __threadfence();               // acquire: invalidate stale cache lines
        #pragma unroll 1
        for (int it = 0; it < BMG / 8; ++it)     // 16 tokens per wave
            route_token(P, out, bm0 + w * (BMG / 8) + it, l);
    }
}

// ---------------- Fallback tier: R6 bf16 3-pass (ws too small for partials) ----
#define BM 16
#define KW 640
#define NS (KW / 32)
#define PS (EE + 1)

__global__ __launch_bounds__(256) void prep_b_bf16(const float* __restrict__ B,
                                                   ushort* __restrict__ Bw) {
    int gid = blockIdx.x * 256 + threadIdx.x;
    int lane = gid & 63;
    int et   = (gid >> 6) % 10;
    int kt   = gid / 640;
    int e = et * 16 + (lane & 15);
    int c = kt * 32 + (lane >> 4) * 8;
    const float* src = B + (size_t)e * HH + c;
    uint4 vh, vl;
    uint32_t hw[8], lw[8];
    #pragma unroll
    for (int j = 0; j < 8; j++) {
        float f = src[j];
        ushort h = f2bf(f);
        float r = f - bf2f(h);
        hw[j] = h;
        lw[j] = f2bf(r);
    }
    vh.x = hw[0] | (hw[1] << 16); vh.y = hw[2] | (hw[3] << 16);
    vh.z = hw[4] | (hw[5] << 16); vh.w = hw[6] | (hw[7] << 16);
    vl.x = lw[0] | (lw[1] << 16); vl.y = lw[2] | (lw[3] << 16);
    vl.z = lw[4] | (lw[5] << 16); vl.w = lw[6] | (lw[7] << 16);
    *reinterpret_cast<uint4*>(Bw + (size_t)gid * 8) = vh;
    *reinterpret_cast<uint4*>(Bw + BW_ELEMS + (size_t)gid * 8) = vl;
}

__device__ __forceinline__ void split8(f32x4 x, f32x4 y, bf16x8& ah, bf16x8& al) {
    float fv[8] = {x[0], x[1], x[2], x[3], y[0], y[1], y[2], y[3]};
    union { uint32_t u[4]; bf16x8 v; } H, L;
    #pragma unroll
    for (int j = 0; j < 4; j++) {
        ushort h0 = f2bf(fv[2*j]), h1 = f2bf(fv[2*j+1]);
        float  r0 = fv[2*j]   - bf2f(h0);
        float  r1 = fv[2*j+1] - bf2f(h1);
        H.u[j] = (uint32_t)h0 | ((uint32_t)h1 << 16);
        L.u[j] = (uint32_t)f2bf(r0) | ((uint32_t)f2bf(r1) << 16);
    }
    ah = H.v; al = L.v;
}

__global__ __launch_bounds__(512, 4) void moe_mfma(const float* __restrict__ A,
                                                   const ushort* __restrict__ Bw,
                                                   float* __restrict__ out) {
    __shared__ float Sc[BM * PS];

    const int tid = threadIdx.x;
    const int w = tid >> 6, l = tid & 63;
    const int bm0 = blockIdx.x * BM;
    const int row  = l & 15;
    const int koct = l >> 4;

    f32x4 acc[10];
    #pragma unroll
    for (int et = 0; et < 10; et++) acc[et] = (f32x4){0.f, 0.f, 0.f, 0.f};

    const float* apw = A + (size_t)(bm0 + row) * HH + w * KW + koct * 8;

    #pragma unroll 1
    for (int s = 0; s < NS; ++s) {
        const f32x4* p = (const f32x4*)(apw + s * 32);
        bf16x8 ah, al;
        split8(p[0], p[1], ah, al);
        const ushort* bt = Bw + ((size_t)((w * NS + s) * 10) * 64 + (size_t)l) * 8;
        #pragma unroll
        for (int et = 0; et < 10; ++et) {
            bf16x8 bh = *(const bf16x8*)(bt + et * 512);
            bf16x8 bl = *(const bf16x8*)(bt + BW_ELEMS + et * 512);
            acc[et] = __builtin_amdgcn_mfma_f32_16x16x32_bf16(ah, bh, acc[et], 0, 0, 0);
            acc[et] = __builtin_amdgcn_mfma_f32_16x16x32_bf16(al, bh, acc[et], 0, 0, 0);
            acc[et] = __builtin_amdgcn_mfma_f32_16x16x32_bf16(ah, bl, acc[et], 0, 0, 0);
        }
    }

    for (int i = tid; i < BM * PS; i += 512) Sc[i] = 0.f;
    __syncthreads();
    const int rrow = koct * 4;
    #pragma unroll
    for (int et = 0; et < 10; et++)
        #pragma unroll
        for (int j = 0; j < 4; j++)
            atomicAdd(&Sc[(rrow + j) * PS + et * 16 + row], acc[et][j]);
    __syncthreads();

    for (int it = 0; it < 2; ++it) {
        const int r = w * 2 + it;
        float s0 = Sc[r * PS + l];
        float s1 = Sc[r * PS + 64 + l];
        float s2 = (l < 32) ? Sc[r * PS + 128 + l] : -INFINITY;

        float m = fmaxf(s0, fmaxf(s1, s2));
        #pragma unroll
        for (int off = 32; off >= 1; off >>= 1) m = fmaxf(m, __shfl_xor(m, off, 64));
        float p0 = expf(s0 - m);
        float p1 = expf(s1 - m);
        float p2 = (l < 32) ? expf(s2 - m) : 0.f;
        float sum = p0 + p1 + p2;
        #pragma unroll
        for (int off = 32; off >= 1; off >>= 1) sum += __shfl_xor(sum, off, 64);
        float inv = 1.0f / sum;
        p0 *= inv; p1 *= inv; p2 *= inv;

        const int g0 = l / GSZ;
        const int g1 = (l + 64) / GSZ;
        const int g2 = (l + 128) / GSZ;

        float gmax[NGRP];
        #pragma unroll
        for (int g = 0; g < NGRP; g++) {
            float v = -1.f;
            if (g0 == g) v = p0;
            if (g1 == g) v = fmaxf(v, p1);
            if (l < 32 && g2 == g) v = fmaxf(v, p2);
            #pragma unroll
            for (int off = 32; off >= 1; off >>= 1) v = fmaxf(v, __shfl_xor(v, off, 64));
            gmax[g] = v;
        }

        int selmask = 0;
        #pragma unroll
        for (int s = 0; s < TOPKG; s++) {
            float best = -2.f; int bg = 0;
            #pragma unroll
            for (int g = 0; g < NGRP; g++)
                if (!((selmask >> g) & 1) && gmax[g] > best) { best = gmax[g]; bg = g; }
            selmask |= 1 << bg;
        }

        float m0 = ((selmask >> g0) & 1) ? p0 : 0.f;
        float m1 = ((selmask >> g1) & 1) ? p1 : 0.f;
        float m2 = (l < 32) ? (((selmask >> g2) & 1) ? p2 : 0.f) : -1.f;

        #pragma unroll
        for (int s = 0; s < TOPK; s++) {
            float v = fmaxf(m0, fmaxf(m1, m2));
            #pragma unroll
            for (int off = 32; off >= 1; off >>= 1) v = fmaxf(v, __shfl_xor(v, off, 64));
            int idx = 0x7fffffff;
            if (m0 == v) idx = l;
            if (m1 == v) idx = min(idx, l + 64);
            if (l < 32 && m2 == v) idx = min(idx, l + 128);
            #pragma unroll
            for (int off = 32; off >= 1; off >>= 1) idx = min(idx, __shfl_xor(idx, off, 64));
            if (idx == l)            m0 = -1.f;
            else if (idx == l + 64)  m1 = -1.f;
            else if (l < 32 && idx == l + 128) m2 = -1.f;
            if (l == 0) out[(size_t)(bm0 + r) * TOPK + s] = v * RSCALE;
        }
    }
}

extern "C" void kernel_launch(void* const* d_in, const int* in_sizes, int n_in,
                              void* d_out, int out_size, void* d_ws, size_t ws_size,
                              hipStream_t stream) {
    const float* hs = (const float*)d_in[0];   // [8192][5120] fp32
    const float* kn = (const float*)d_in[1];   // [160][5120] fp32
    float* o = (float*)d_out;                  // [8192][6] fp32

    const size_t pBytes = (size_t)SK * TT * EE * 4;          // 41,943,040 (fp32)
    const size_t cBytes = NMB * sizeof(int);                 // 256
    if (ws_size >= BWH_BYTES + pBytes + cBytes) {
        ushort* Bw  = (ushort*)d_ws;
        float*  P   = (float*)((char*)d_ws + BWH_BYTES);
        int*    cnt = (int*)((char*)d_ws + BWH_BYTES + pBytes);
        hipLaunchKernelGGL(prep_b_f16, dim3(400),     dim3(256), 0, stream, kn, Bw, cnt);
        hipLaunchKernelGGL(moe_gemm,   dim3(64 * SK), dim3(512), 0, stream, hs, Bw, P, cnt, o);
    } else {
        ushort* Bw = (ushort*)d_ws;
        hipLaunchKernelGGL(prep_b_bf16, dim3(400),    dim3(256), 0, stream, kn, Bw);
        hipLaunchKernelGGL(moe_mfma,   dim3(TT / BM), dim3(512), 0, stream, hs, Bw, o);
    }
}

// Round 17
// 59.253 us; speedup vs baseline: 4.8828x; 4.8828x over previous
//
#include <hip/hip_runtime.h>
#include <math.h>

#define TT 8192
#define HH 5120
#define EE 160
#define NGRP 8
#define GSZ 20
#define TOPKG 3
#define TOPK 6
#define RSCALE 16.0f
#define SK 8              // split-K factor
#define KS (HH / SK)      // 640 K per slice
#define NSG (KS / 32)     // 20 K32 steps per gemm block
#define BMG 128           // tokens per gemm block -> grid 64*8=512, 2 blocks/CU

typedef __attribute__((ext_vector_type(8))) short bf16x8;
typedef __attribute__((ext_vector_type(8))) _Float16 f16x8;
typedef __attribute__((ext_vector_type(4))) float f32x4;

#define BW_ELEMS ((size_t)160 * 10 * 64 * 8)     // 819200 frag elements per copy
#define BWH_BYTES (BW_ELEMS * 2)                 // 1,638,400 bytes (f16 single copy)

__device__ __forceinline__ ushort f2bf(float f) {
    uint32_t u = __float_as_uint(f);
    u += 0x7fff + ((u >> 16) & 1);   // RNE
    return (ushort)(u >> 16);
}
__device__ __forceinline__ float bf2f(ushort h) {
    return __uint_as_float(((uint32_t)h) << 16);
}

// pack 8 fp32 -> 8 f16 (RNE via _Float16 cast; v_cvt_f16_f32 is RNE)
__device__ __forceinline__ f16x8 cvt8(f32x4 x, f32x4 y) {
    f16x8 r;
    r[0] = (_Float16)x[0]; r[1] = (_Float16)x[1];
    r[2] = (_Float16)x[2]; r[3] = (_Float16)x[3];
    r[4] = (_Float16)y[0]; r[5] = (_Float16)y[1];
    r[6] = (_Float16)y[2]; r[7] = (_Float16)y[3];
    return r;
}

// ---------------- Kernel 1: B [160][5120] fp32 -> f16 fragment-linear ----------
// layout: [kt 0..159][et 0..9][lane 0..63][8 f16]; lane&15 = expert,
// lane>>4 = k-octet -> mfma_f32_16x16x32_f16 B-operand frag.
__global__ __launch_bounds__(256) void prep_b_f16(const float* __restrict__ B,
                                                  ushort* __restrict__ Bw) {
    int gid = blockIdx.x * 256 + threadIdx.x;        // < 102400
    int lane = gid & 63;
    int et   = (gid >> 6) % 10;
    int kt   = gid / 640;
    int e = et * 16 + (lane & 15);
    int c = kt * 32 + (lane >> 4) * 8;
    const float* src = B + (size_t)e * HH + c;
    f32x4 s0 = *(const f32x4*)src;
    f32x4 s1 = *(const f32x4*)(src + 4);
    union { f16x8 h; uint4 v; } u;
    u.h = cvt8(s0, s1);
    *reinterpret_cast<uint4*>(Bw + (size_t)gid * 8) = u.v;
}

// ---------------- Kernel 2: split-K GEMM (f16), B shared via LDS ---------------
// R10 configuration — session best at 59.6us. Block = 128 tokens x 640 K,
// 8 waves, wave w owns rows [16w,16w+16). BK=32. Grid 512 = 2 blocks/CU.
// One __syncthreads per step. Partials -> P[ks][token][expert] fp32.
// NOTE (R15): fusing routing into this kernel makes the compiler spill acc
// (VGPR 44, MfmaUtil 1.6%, 5.5x slower) — keep routing as a separate kernel.
__global__ __launch_bounds__(512, 4) void moe_gemm(const float* __restrict__ A,
                                                   const ushort* __restrict__ Bw,
                                                   float* __restrict__ P) {
    __shared__ char lds[2][10240];     // double-buffered K32 B tile (f16)

    const int tid = threadIdx.x;
    const int w = tid >> 6, l = tid & 63;
    const int mb  = blockIdx.x & 63;   // token-block (64)
    const int ks  = blockIdx.x >> 6;   // k-slice (8)
    const int bm0 = mb * BMG;
    const int kt0 = ks * NSG;          // global K32-tile base

    const int row = l & 15, koct = l >> 4;

    // A pointer: this wave's m-tile row (16w + row), k base ks*KS + koct*8
    const float* apA = A + (size_t)(bm0 + 16 * w + row) * HH + ks * KS + koct * 8;

    // staging: 640 16B-units per step; u0 for all 512 threads, u1 for tid<128
    const char* BwB = (const char*)Bw;
    const int u0 = tid, u1 = tid + 512;

    f32x4 acc[10];
    #pragma unroll
    for (int et = 0; et < 10; et++) acc[et] = (f32x4){0.f, 0.f, 0.f, 0.f};

    // ---- prologue: stage step 0 + load A(step 0)
    {
        size_t tb = (size_t)kt0 * 10240;
        uint4 r0 = *(const uint4*)(BwB + tb + (size_t)u0 * 16);
        *(uint4*)(lds[0] + u0 * 16) = r0;
        if (tid < 128) {
            uint4 r1 = *(const uint4*)(BwB + tb + (size_t)u1 * 16);
            *(uint4*)(lds[0] + u1 * 16) = r1;
        }
    }
    f32x4 pa0 = *(const f32x4*)(apA), pa1 = *(const f32x4*)(apA + 4);
    __syncthreads();

    #pragma unroll 1
    for (int s = 0; s < NSG; ++s) {
        const int cur = s & 1;
        const bool more = (s + 1 < NSG);

        // ---- issue global loads for s+1 FIRST (latency hides under compute)
        uint4 n0, n1;
        f32x4 na0 = pa0, na1 = pa1;
        if (more) {
            size_t tb = (size_t)(kt0 + s + 1) * 10240;
            n0 = *(const uint4*)(BwB + tb + (size_t)u0 * 16);
            if (tid < 128) n1 = *(const uint4*)(BwB + tb + (size_t)u1 * 16);
            const float* a = apA + (s + 1) * 32;
            na0 = *(const f32x4*)(a); na1 = *(const f32x4*)(a + 4);
        }

        // ---- convert current A (already in regs) and compute from buf[cur]
        f16x8 a16 = cvt8(pa0, pa1);
        const char* LB = lds[cur];
        #pragma unroll
        for (int et = 0; et < 10; ++et) {
            f16x8 bh = *(const f16x8*)(LB + et * 1024 + l * 16);
            acc[et] = __builtin_amdgcn_mfma_f32_16x16x32_f16(a16, bh, acc[et], 0, 0, 0);
        }

        // ---- stage s+1 into the other buffer (safe: readers passed barrier s-1)
        if (more) {
            char* LN = lds[1 - cur];
            *(uint4*)(LN + u0 * 16) = n0;
            if (tid < 128) *(uint4*)(LN + u1 * 16) = n1;
        }
        pa0 = na0; pa1 = na1;
        __syncthreads();               // one barrier per step
    }

    // ---- write fp32 partials: P[ks][bm0 + 16w + (l>>4)*4 + j][et*16 + (l&15)]
    const int rrow = koct * 4;
    #pragma unroll
    for (int et = 0; et < 10; et++)
        #pragma unroll
        for (int j = 0; j < 4; j++)
            P[((size_t)ks * TT + bm0 + 16 * w + rrow + j) * EE + et * 16 + row]
                = acc[et][j];
}

// ---------------- Kernel 3: reduce K-slices + softmax + group-topk routing -----
__global__ __launch_bounds__(512, 4) void moe_route(const float* __restrict__ P,
                                                    float* __restrict__ out) {
    const int w = threadIdx.x >> 6, l = threadIdx.x & 63;
    const int t = blockIdx.x * 8 + w;   // token

    float s0 = 0.f, s1 = 0.f, s2 = 0.f;
    #pragma unroll
    for (int sl = 0; sl < SK; ++sl) {
        const float* b = P + ((size_t)sl * TT + t) * EE;
        s0 += b[l];
        s1 += b[64 + l];
        if (l < 32) s2 += b[128 + l];
    }
    if (l >= 32) s2 = -INFINITY;

    // ---- softmax over 160 (validated R0/R2)
    float m = fmaxf(s0, fmaxf(s1, s2));
    #pragma unroll
    for (int off = 32; off >= 1; off >>= 1) m = fmaxf(m, __shfl_xor(m, off, 64));
    float p0 = expf(s0 - m);
    float p1 = expf(s1 - m);
    float p2 = (l < 32) ? expf(s2 - m) : 0.f;
    float sum = p0 + p1 + p2;
    #pragma unroll
    for (int off = 32; off >= 1; off >>= 1) sum += __shfl_xor(sum, off, 64);
    float inv = 1.0f / sum;
    p0 *= inv; p1 *= inv; p2 *= inv;

    const int g0 = l / GSZ;
    const int g1 = (l + 64) / GSZ;
    const int g2 = (l + 128) / GSZ;

    float gmax[NGRP];
    #pragma unroll
    for (int g = 0; g < NGRP; g++) {
        float v = -1.f;
        if (g0 == g) v = p0;
        if (g1 == g) v = fmaxf(v, p1);
        if (l < 32 && g2 == g) v = fmaxf(v, p2);
        #pragma unroll
        for (int off = 32; off >= 1; off >>= 1) v = fmaxf(v, __shfl_xor(v, off, 64));
        gmax[g] = v;
    }

    int selmask = 0;
    #pragma unroll
    for (int s = 0; s < TOPKG; s++) {
        float best = -2.f; int bg = 0;
        #pragma unroll
        for (int g = 0; g < NGRP; g++)
            if (!((selmask >> g) & 1) && gmax[g] > best) { best = gmax[g]; bg = g; }
        selmask |= 1 << bg;
    }

    float m0 = ((selmask >> g0) & 1) ? p0 : 0.f;
    float m1 = ((selmask >> g1) & 1) ? p1 : 0.f;
    float m2 = (l < 32) ? (((selmask >> g2) & 1) ? p2 : 0.f) : -1.f;

    #pragma unroll
    for (int s = 0; s < TOPK; s++) {
        float v = fmaxf(m0, fmaxf(m1, m2));
        #pragma unroll
        for (int off = 32; off >= 1; off >>= 1) v = fmaxf(v, __shfl_xor(v, off, 64));
        int idx = 0x7fffffff;
        if (m0 == v) idx = l;
        if (m1 == v) idx = min(idx, l + 64);
        if (l < 32 && m2 == v) idx = min(idx, l + 128);
        #pragma unroll
        for (int off = 32; off >= 1; off >>= 1) idx = min(idx, __shfl_xor(idx, off, 64));
        if (idx == l)            m0 = -1.f;
        else if (idx == l + 64)  m1 = -1.f;
        else if (l < 32 && idx == l + 128) m2 = -1.f;
        if (l == 0) out[(size_t)t * TOPK + s] = v * RSCALE;
    }
}

// ---------------- Fallback tier: R6 bf16 3-pass (ws too small for partials) ----
#define BM 16
#define KW 640
#define NS (KW / 32)
#define PS (EE + 1)

__global__ __launch_bounds__(256) void prep_b_bf16(const float* __restrict__ B,
                                                   ushort* __restrict__ Bw) {
    int gid = blockIdx.x * 256 + threadIdx.x;
    int lane = gid & 63;
    int et   = (gid >> 6) % 10;
    int kt   = gid / 640;
    int e = et * 16 + (lane & 15);
    int c = kt * 32 + (lane >> 4) * 8;
    const float* src = B + (size_t)e * HH + c;
    uint4 vh, vl;
    uint32_t hw[8], lw[8];
    #pragma unroll
    for (int j = 0; j < 8; j++) {
        float f = src[j];
        ushort h = f2bf(f);
        float r = f - bf2f(h);
        hw[j] = h;
        lw[j] = f2bf(r);
    }
    vh.x = hw[0] | (hw[1] << 16); vh.y = hw[2] | (hw[3] << 16);
    vh.z = hw[4] | (hw[5] << 16); vh.w = hw[6] | (hw[7] << 16);
    vl.x = lw[0] | (lw[1] << 16); vl.y = lw[2] | (lw[3] << 16);
    vl.z = lw[4] | (lw[5] << 16); vl.w = lw[6] | (lw[7] << 16);
    *reinterpret_cast<uint4*>(Bw + (size_t)gid * 8) = vh;
    *reinterpret_cast<uint4*>(Bw + BW_ELEMS + (size_t)gid * 8) = vl;
}

__device__ __forceinline__ void split8(f32x4 x, f32x4 y, bf16x8& ah, bf16x8& al) {
    float fv[8] = {x[0], x[1], x[2], x[3], y[0], y[1], y[2], y[3]};
    union { uint32_t u[4]; bf16x8 v; } H, L;
    #pragma unroll
    for (int j = 0; j < 4; j++) {
        ushort h0 = f2bf(fv[2*j]), h1 = f2bf(fv[2*j+1]);
        float  r0 = fv[2*j]   - bf2f(h0);
        float  r1 = fv[2*j+1] - bf2f(h1);
        H.u[j] = (uint32_t)h0 | ((uint32_t)h1 << 16);
        L.u[j] = (uint32_t)f2bf(r0) | ((uint32_t)f2bf(r1) << 16);
    }
    ah = H.v; al = L.v;
}

__global__ __launch_bounds__(512, 4) void moe_mfma(const float* __restrict__ A,
                                                   const ushort* __restrict__ Bw,
                                                   float* __restrict__ out) {
    __shared__ float Sc[BM * PS];

    const int tid = threadIdx.x;
    const int w = tid >> 6, l = tid & 63;
    const int bm0 = blockIdx.x * BM;
    const int row  = l & 15;
    const int koct = l >> 4;

    f32x4 acc[10];
    #pragma unroll
    for (int et = 0; et < 10; et++) acc[et] = (f32x4){0.f, 0.f, 0.f, 0.f};

    const float* apw = A + (size_t)(bm0 + row) * HH + w * KW + koct * 8;

    #pragma unroll 1
    for (int s = 0; s < NS; ++s) {
        const f32x4* p = (const f32x4*)(apw + s * 32);
        bf16x8 ah, al;
        split8(p[0], p[1], ah, al);
        const ushort* bt = Bw + ((size_t)((w * NS + s) * 10) * 64 + (size_t)l) * 8;
        #pragma unroll
        for (int et = 0; et < 10; ++et) {
            bf16x8 bh = *(const bf16x8*)(bt + et * 512);
            bf16x8 bl = *(const bf16x8*)(bt + BW_ELEMS + et * 512);
            acc[et] = __builtin_amdgcn_mfma_f32_16x16x32_bf16(ah, bh, acc[et], 0, 0, 0);
            acc[et] = __builtin_amdgcn_mfma_f32_16x16x32_bf16(al, bh, acc[et], 0, 0, 0);
            acc[et] = __builtin_amdgcn_mfma_f32_16x16x32_bf16(ah, bl, acc[et], 0, 0, 0);
        }
    }

    for (int i = tid; i < BM * PS; i += 512) Sc[i] = 0.f;
    __syncthreads();
    const int rrow = koct * 4;
    #pragma unroll
    for (int et = 0; et < 10; et++)
        #pragma unroll
        for (int j = 0; j < 4; j++)
            atomicAdd(&Sc[(rrow + j) * PS + et * 16 + row], acc[et][j]);
    __syncthreads();

    for (int it = 0; it < 2; ++it) {
        const int r = w * 2 + it;
        float s0 = Sc[r * PS + l];
        float s1 = Sc[r * PS + 64 + l];
        float s2 = (l < 32) ? Sc[r * PS + 128 + l] : -INFINITY;

        float m = fmaxf(s0, fmaxf(s1, s2));
        #pragma unroll
        for (int off = 32; off >= 1; off >>= 1) m = fmaxf(m, __shfl_xor(m, off, 64));
        float p0 = expf(s0 - m);
        float p1 = expf(s1 - m);
        float p2 = (l < 32) ? expf(s2 - m) : 0.f;
        float sum = p0 + p1 + p2;
        #pragma unroll
        for (int off = 32; off >= 1; off >>= 1) sum += __shfl_xor(sum, off, 64);
        float inv = 1.0f / sum;
        p0 *= inv; p1 *= inv; p2 *= inv;

        const int g0 = l / GSZ;
        const int g1 = (l + 64) / GSZ;
        const int g2 = (l + 128) / GSZ;

        float gmax[NGRP];
        #pragma unroll
        for (int g = 0; g < NGRP; g++) {
            float v = -1.f;
            if (g0 == g) v = p0;
            if (g1 == g) v = fmaxf(v, p1);
            if (l < 32 && g2 == g) v = fmaxf(v, p2);
            #pragma unroll
            for (int off = 32; off >= 1; off >>= 1) v = fmaxf(v, __shfl_xor(v, off, 64));
            gmax[g] = v;
        }

        int selmask = 0;
        #pragma unroll
        for (int s = 0; s < TOPKG; s++) {
            float best = -2.f; int bg = 0;
            #pragma unroll
            for (int g = 0; g < NGRP; g++)
                if (!((selmask >> g) & 1) && gmax[g] > best) { best = gmax[g]; bg = g; }
            selmask |= 1 << bg;
        }

        float m0 = ((selmask >> g0) & 1) ? p0 : 0.f;
        float m1 = ((selmask >> g1) & 1) ? p1 : 0.f;
        float m2 = (l < 32) ? (((selmask >> g2) & 1) ? p2 : 0.f) : -1.f;

        #pragma unroll
        for (int s = 0; s < TOPK; s++) {
            float v = fmaxf(m0, fmaxf(m1, m2));
            #pragma unroll
            for (int off = 32; off >= 1; off >>= 1) v = fmaxf(v, __shfl_xor(v, off, 64));
            int idx = 0x7fffffff;
            if (m0 == v) idx = l;
            if (m1 == v) idx = min(idx, l + 64);
            if (l < 32 && m2 == v) idx = min(idx, l + 128);
            #pragma unroll
            for (int off = 32; off >= 1; off >>= 1) idx = min(idx, __shfl_xor(idx, off, 64));
            if (idx == l)            m0 = -1.f;
            else if (idx == l + 64)  m1 = -1.f;
            else if (l < 32 && idx == l + 128) m2 = -1.f;
            if (l == 0) out[(size_t)(bm0 + r) * TOPK + s] = v * RSCALE;
        }
    }
}

extern "C" void kernel_launch(void* const* d_in, const int* in_sizes, int n_in,
                              void* d_out, int out_size, void* d_ws, size_t ws_size,
                              hipStream_t stream) {
    const float* hs = (const float*)d_in[0];   // [8192][5120] fp32
    const float* kn = (const float*)d_in[1];   // [160][5120] fp32
    float* o = (float*)d_out;                  // [8192][6] fp32

    const size_t pBytes = (size_t)SK * TT * EE * 4;          // 41,943,040 (fp32)
    if (ws_size >= BWH_BYTES + pBytes) {
        ushort* Bw = (ushort*)d_ws;
        float*  P  = (float*)((char*)d_ws + BWH_BYTES);
        hipLaunchKernelGGL(prep_b_f16, dim3(400),     dim3(256), 0, stream, kn, Bw);
        hipLaunchKernelGGL(moe_gemm,   dim3(64 * SK), dim3(512), 0, stream, hs, Bw, P);
        hipLaunchKernelGGL(moe_route,  dim3(TT / 8),  dim3(512), 0, stream, P, o);
    } else {
        ushort* Bw = (ushort*)d_ws;
        hipLaunchKernelGGL(prep_b_bf16, dim3(400),    dim3(256), 0, stream, hs ? kn : kn, Bw);
        hipLaunchKernelGGL(moe_mfma,   dim3(TT / BM), dim3(512), 0, stream, hs, Bw, o);
    }
}